// Round 1
// baseline (321.155 us; speedup 1.0000x reference)
//
#include <hip/hip_runtime.h>
#include <stdint.h>
#include <stddef.h>

typedef __attribute__((ext_vector_type(8))) short bf16x8;
typedef __attribute__((ext_vector_type(4))) short bf16x4;
typedef __attribute__((ext_vector_type(4))) float f32x4;

#define MFMA16x16x32 __builtin_amdgcn_mfma_f32_16x16x32_bf16
#define L2E 1.4426950408889634f

__device__ __forceinline__ short f2bf(float f) {
  union { float f; uint32_t u; } c; c.f = f;
  uint32_t r = c.u + 0x7fffu + ((c.u >> 16) & 1u);
  return (short)(r >> 16);
}

// ---------------- x transpose: [B][512][4096] f32 -> [B][4096][512] bf16
__global__ __launch_bounds__(256) void k_transpose_x(const float* __restrict__ x,
                                                     short* __restrict__ xt) {
  __shared__ float tile[32][33];
  const int b = blockIdx.z;
  const int s0 = blockIdx.x * 32, k0 = blockIdx.y * 32;
  const int tx = threadIdx.x, ty = threadIdx.y;
  const float* xp = x + ((size_t)b * 512 + k0) * 4096 + s0;
#pragma unroll
  for (int i = 0; i < 32; i += 8) tile[ty + i][tx] = xp[(size_t)(ty + i) * 4096 + tx];
  __syncthreads();
  short* op = xt + ((size_t)b * 4096 + s0) * 512 + k0;
#pragma unroll
  for (int i = 0; i < 32; i += 8) op[(size_t)(ty + i) * 512 + tx] = f2bf(tile[tx][ty + i]);
}

// ---------------- W transpose: [512 k][512 h] f32 -> [512 h][512 k] bf16, *scale
__global__ __launch_bounds__(256) void k_transpose_w(const float* __restrict__ w,
                                                     short* __restrict__ wt, float scale) {
  __shared__ float tile[32][33];
  const int h0 = blockIdx.x * 32, k0 = blockIdx.y * 32;
  const int tx = threadIdx.x, ty = threadIdx.y;
#pragma unroll
  for (int i = 0; i < 32; i += 8) tile[ty + i][tx] = w[(size_t)(k0 + ty + i) * 512 + h0 + tx];
  __syncthreads();
#pragma unroll
  for (int i = 0; i < 32; i += 8)
    wt[(size_t)(h0 + ty + i) * 512 + k0 + tx] = f2bf(tile[tx][ty + i] * scale);
}

// ---------------- projection GEMM: C[m][h] = sum_k A[m][k]*Bt[h][k] + bias[h]*bscale
// A: Xt [16384][512] bf16, Bt: Wt [512][512] bf16.
// vmode 0: out bf16 [16384][512] row-major. vmode 1: out bf16 VT[b][h][s] (b=m>>12, s=m&4095)
__global__ __launch_bounds__(256) void k_proj_gemm(const short* __restrict__ A,
                                                   const short* __restrict__ Bt,
                                                   const float* __restrict__ bias,
                                                   short* __restrict__ outp,
                                                   float bscale, int vmode) {
  __shared__ short As[128 * 64];
  __shared__ short Bs[128 * 64];
  const int tid = threadIdx.x, lane = tid & 63, wave = tid >> 6;
  const int m0 = blockIdx.x * 128, h0 = blockIdx.y * 128;
  const int wm = wave >> 1, wn = wave & 1;  // 2x2 wave grid, 64x64 each

  f32x4 acc[4][4];
#pragma unroll
  for (int fh = 0; fh < 4; ++fh) {
    float bv = bias[h0 + 64 * wn + 16 * fh + (lane & 15)] * bscale;
#pragma unroll
    for (int fm = 0; fm < 4; ++fm) acc[fm][fh] = (f32x4){bv, bv, bv, bv};
  }

  for (int k0 = 0; k0 < 512; k0 += 64) {
#pragma unroll
    for (int it = 0; it < 4; ++it) {
      int p = it * 256 + tid;      // 16B chunk id, 0..1023
      int row = p >> 3;            // 0..127
      int c = p & 7;               // logical chunk within 128B row
      int pc = c ^ (row & 7);      // swizzled
      bf16x8 va = *(const bf16x8*)(A + (size_t)(m0 + row) * 512 + k0 + c * 8);
      bf16x8 vb = *(const bf16x8*)(Bt + (size_t)(h0 + row) * 512 + k0 + c * 8);
      *(bf16x8*)(As + row * 64 + pc * 8) = va;
      *(bf16x8*)(Bs + row * 64 + pc * 8) = vb;
    }
    __syncthreads();
#pragma unroll
    for (int kk = 0; kk < 2; ++kk) {
      bf16x8 af[4], bf[4];
#pragma unroll
      for (int f = 0; f < 4; ++f) {
        int ra = 64 * wm + 16 * f + (lane & 15);
        int ca = (4 * kk + (lane >> 4)) ^ (ra & 7);
        af[f] = *(const bf16x8*)(As + ra * 64 + ca * 8);
        int rb = 64 * wn + 16 * f + (lane & 15);
        int cb = (4 * kk + (lane >> 4)) ^ (rb & 7);
        bf[f] = *(const bf16x8*)(Bs + rb * 64 + cb * 8);
      }
#pragma unroll
      for (int fm = 0; fm < 4; ++fm)
#pragma unroll
        for (int fh = 0; fh < 4; ++fh)
          acc[fm][fh] = MFMA16x16x32(af[fm], bf[fh], acc[fm][fh], 0, 0, 0);
    }
    __syncthreads();
  }

  if (vmode == 0) {
#pragma unroll
    for (int fm = 0; fm < 4; ++fm) {
      int rbase = m0 + 64 * wm + 16 * fm + (lane >> 4) * 4;
#pragma unroll
      for (int fh = 0; fh < 4; ++fh) {
        int h = h0 + 64 * wn + 16 * fh + (lane & 15);
#pragma unroll
        for (int j = 0; j < 4; ++j)
          outp[(size_t)(rbase + j) * 512 + h] = f2bf(acc[fm][fh][j]);
      }
    }
  } else {
#pragma unroll
    for (int fm = 0; fm < 4; ++fm) {
      int m = m0 + 64 * wm + 16 * fm + (lane >> 4) * 4;
      int b = m >> 12, s = m & 4095;
#pragma unroll
      for (int fh = 0; fh < 4; ++fh) {
        int h = h0 + 64 * wn + 16 * fh + (lane & 15);
        bf16x4 v;
#pragma unroll
        for (int j = 0; j < 4; ++j) v[j] = f2bf(acc[fm][fh][j]);
        *(bf16x4*)(outp + ((size_t)b * 512 + h) * 4096 + s) = v;
      }
    }
  }
}

// ---------------- fused flash attention
// Qg,Kg: [B][4096][512] bf16 (Q pre-scaled by 1/sqrt(512)); VTg: [B][512][4096] bf16
// out: [B][512][4096] f32
__global__ __launch_bounds__(512) void k_attn(const short* __restrict__ Qg,
                                              const short* __restrict__ Kg,
                                              const short* __restrict__ VTg,
                                              float* __restrict__ out) {
  __shared__ short KVs[64 * 512];   // 64KB: K tile [64][512] then VT tile [512][64]
  __shared__ float Sbuf[64][68];    // scores fp32
  __shared__ short Pbuf[64 * 64];   // P bf16, swizzled
  __shared__ float mrun[64], lrun[64], corrbuf[64];

  const int tid = threadIdx.x, lane = tid & 63, wave = tid >> 6;
  const int b = blockIdx.y, qb = blockIdx.x;
  const int s0 = qb * 64;
  const int mi = wave >> 1, nj = wave & 1;  // QK^T mapping: 4 x 2
  const int pm = wave >> 2, ph = wave & 3;  // PV mapping:   2 x 4

  const short* Qb = Qg + (size_t)b * 4096 * 512;
  const short* Kb = Kg + (size_t)b * 4096 * 512;
  const short* VTb = VTg + (size_t)b * 512 * 4096;

  // Q rows for this wave's QK^T m-frag, kept in registers (16 chunks x 8 bf16)
  bf16x8 qreg[16];
  {
    const short* qp = Qb + (size_t)(s0 + 16 * mi + (lane & 15)) * 512 + 8 * (lane >> 4);
#pragma unroll
    for (int c = 0; c < 16; ++c) qreg[c] = *(const bf16x8*)(qp + 32 * c);
  }
  f32x4 of[2][8];
#pragma unroll
  for (int i = 0; i < 2; ++i)
#pragma unroll
    for (int j = 0; j < 8; ++j) of[i][j] = (f32x4){0.f, 0.f, 0.f, 0.f};
  if (tid < 64) { mrun[tid] = -1e30f; lrun[tid] = 0.f; }

  for (int t = 0; t < 64; ++t) {
    const int kv0 = t * 64;
    // ---- phase A: stage K tile [64][512], rows 1024B = 64 chunks, swz low3
#pragma unroll
    for (int it = 0; it < 8; ++it) {
      int row = it * 8 + wave;
      int pc = lane ^ (row & 7);
      *(bf16x8*)(KVs + row * 512 + pc * 8) =
          *(const bf16x8*)(Kb + (size_t)(kv0 + row) * 512 + lane * 8);
    }
    __syncthreads();
    // ---- phase B: QK^T
    f32x4 sf[2];
    sf[0] = (f32x4){0.f, 0.f, 0.f, 0.f};
    sf[1] = (f32x4){0.f, 0.f, 0.f, 0.f};
#pragma unroll
    for (int kk = 0; kk < 16; ++kk) {
#pragma unroll
      for (int f = 0; f < 2; ++f) {
        int r = 32 * nj + 16 * f + (lane & 15);
        int pc = (4 * kk + (lane >> 4)) ^ (r & 7);
        bf16x8 kb = *(const bf16x8*)(KVs + r * 512 + pc * 8);
        sf[f] = MFMA16x16x32(qreg[kk], kb, sf[f], 0, 0, 0);
      }
    }
#pragma unroll
    for (int f = 0; f < 2; ++f) {
      int col = 32 * nj + 16 * f + (lane & 15);
      int rb2 = 16 * mi + (lane >> 4) * 4;
#pragma unroll
      for (int j = 0; j < 4; ++j) Sbuf[rb2 + j][col] = sf[f][j];
    }
    __syncthreads();
    // ---- phase C: stage VT tile [512][64] into KVs (K no longer needed) + softmax
#pragma unroll
    for (int it = 0; it < 8; ++it) {
      int h = it * 64 + wave * 8 + (lane >> 3);
      int c = lane & 7;
      int pc = c ^ (h & 7);
      *(bf16x8*)(KVs + h * 64 + pc * 8) =
          *(const bf16x8*)(VTb + (size_t)h * 4096 + kv0 + c * 8);
    }
    {
      int row = tid >> 3, sub = tid & 7;
      f32x4 sa = *(const f32x4*)&Sbuf[row][sub * 8];
      f32x4 sb = *(const f32x4*)&Sbuf[row][sub * 8 + 4];
      float rmax = fmaxf(fmaxf(fmaxf(sa[0], sa[1]), fmaxf(sa[2], sa[3])),
                         fmaxf(fmaxf(sb[0], sb[1]), fmaxf(sb[2], sb[3])));
      rmax = fmaxf(rmax, __shfl_xor(rmax, 1));
      rmax = fmaxf(rmax, __shfl_xor(rmax, 2));
      rmax = fmaxf(rmax, __shfl_xor(rmax, 4));
      float mold = mrun[row];
      float mnew = fmaxf(mold, rmax);
      float p[8], psum = 0.f;
#pragma unroll
      for (int j = 0; j < 4; ++j) p[j] = exp2f((sa[j] - mnew) * L2E);
#pragma unroll
      for (int j = 0; j < 4; ++j) p[4 + j] = exp2f((sb[j] - mnew) * L2E);
      bf16x8 pv;
#pragma unroll
      for (int j = 0; j < 8; ++j) { psum += p[j]; pv[j] = f2bf(p[j]); }
      int pc = sub ^ (row & 7);
      *(bf16x8*)(Pbuf + row * 64 + pc * 8) = pv;
      psum += __shfl_xor(psum, 1);
      psum += __shfl_xor(psum, 2);
      psum += __shfl_xor(psum, 4);
      if (sub == 0) {
        float corr = exp2f((mold - mnew) * L2E);
        lrun[row] = lrun[row] * corr + psum;
        mrun[row] = mnew;
        corrbuf[row] = corr;
      }
    }
    __syncthreads();
    // ---- phase D: rescale O, then PV
#pragma unroll
    for (int fm = 0; fm < 2; ++fm) {
      int rb2 = 32 * pm + 16 * fm + (lane >> 4) * 4;
#pragma unroll
      for (int j = 0; j < 4; ++j) {
        float corr = corrbuf[rb2 + j];
#pragma unroll
        for (int fh = 0; fh < 8; ++fh) of[fm][fh][j] *= corr;
      }
    }
#pragma unroll
    for (int ks = 0; ks < 2; ++ks) {
      bf16x8 pa[2];
#pragma unroll
      for (int fm = 0; fm < 2; ++fm) {
        int r = 32 * pm + 16 * fm + (lane & 15);
        int pc = (4 * ks + (lane >> 4)) ^ (r & 7);
        pa[fm] = *(const bf16x8*)(Pbuf + r * 64 + pc * 8);
      }
#pragma unroll
      for (int fh = 0; fh < 8; ++fh) {
        int n = 128 * ph + 16 * fh + (lane & 15);
        int pc = (4 * ks + (lane >> 4)) ^ (n & 7);
        bf16x8 vb = *(const bf16x8*)(KVs + n * 64 + pc * 8);
#pragma unroll
        for (int fm = 0; fm < 2; ++fm) of[fm][fh] = MFMA16x16x32(pa[fm], vb, of[fm][fh], 0, 0, 0);
      }
    }
    __syncthreads();
  }
  // ---- epilogue: O /= l, write out[b][h][s]
#pragma unroll
  for (int fm = 0; fm < 2; ++fm) {
    int rb2 = 32 * pm + 16 * fm + (lane >> 4) * 4;
    float inv[4];
#pragma unroll
    for (int j = 0; j < 4; ++j) inv[j] = 1.f / lrun[rb2 + j];
#pragma unroll
    for (int fh = 0; fh < 8; ++fh) {
      int h = 128 * ph + 16 * fh + (lane & 15);
      f32x4 v;
#pragma unroll
      for (int j = 0; j < 4; ++j) v[j] = of[fm][fh][j] * inv[j];
      *(f32x4*)(out + ((size_t)b * 512 + h) * 4096 + s0 + rb2) = v;
    }
  }
}

extern "C" void kernel_launch(void* const* d_in, const int* in_sizes, int n_in,
                              void* d_out, int out_size, void* d_ws, size_t ws_size,
                              hipStream_t stream) {
  (void)in_sizes; (void)n_in; (void)out_size; (void)ws_size;
  const float* x = (const float*)d_in[0];
  const float* Wq = (const float*)d_in[1];
  const float* bq = (const float*)d_in[2];
  const float* Wk = (const float*)d_in[3];
  const float* bk = (const float*)d_in[4];
  const float* Wv = (const float*)d_in[5];
  const float* bv = (const float*)d_in[6];
  float* out = (float*)d_out;
  char* ws = (char*)d_ws;

  // workspace layout (bytes)
  short* xt  = (short*)(ws + 0);          // 16,777,216  Xt  [B][S][512] bf16
  short* qg  = (short*)(ws + 16777216);   // 16,777,216  Q   [B][S][512] bf16 (pre-scaled)
  short* kg  = (short*)(ws + 33554432);   // 16,777,216  K   [B][S][512] bf16
  short* vtg = (short*)(ws + 50331648);   // 16,777,216  V^T [B][512][S] bf16
  short* wqt = (short*)(ws + 67108864);   // 524,288     Wq^T bf16 (scaled)
  short* wkt = (short*)(ws + 67633152);   // 524,288
  short* wvt = (short*)(ws + 68157440);   // 524,288     (total 68,681,728 B)

  const float scale = 0.04419417382415922f;  // 1/sqrt(512)

  k_transpose_x<<<dim3(128, 16, 4), dim3(32, 8), 0, stream>>>(x, xt);
  k_transpose_w<<<dim3(16, 16), dim3(32, 8), 0, stream>>>(Wq, wqt, scale);
  k_transpose_w<<<dim3(16, 16), dim3(32, 8), 0, stream>>>(Wk, wkt, 1.0f);
  k_transpose_w<<<dim3(16, 16), dim3(32, 8), 0, stream>>>(Wv, wvt, 1.0f);

  k_proj_gemm<<<dim3(128, 4), 256, 0, stream>>>(xt, wqt, bq, qg, scale, 0);
  k_proj_gemm<<<dim3(128, 4), 256, 0, stream>>>(xt, wkt, bk, kg, 1.0f, 0);
  k_proj_gemm<<<dim3(128, 4), 256, 0, stream>>>(xt, wvt, bv, vtg, 1.0f, 1);

  k_attn<<<dim3(64, 4), 512, 0, stream>>>(qg, kg, vtg, out);
}